// Round 1
// baseline (1062.317 us; speedup 1.0000x reference)
//
#include <hip/hip_runtime.h>
#include <hip/hip_bf16.h>

typedef unsigned short u16;
typedef __attribute__((ext_vector_type(8))) short bf16x8;
typedef __attribute__((ext_vector_type(4))) float f32x4;

#define N_NODES 50000
#define EDGES 500000

__device__ __forceinline__ u16 f2bf(float f) {
  return __builtin_bit_cast(u16, __float2bfloat16(f));
}
__device__ __forceinline__ float bf2f(u16 u) {
  return __builtin_bit_cast(float, ((unsigned)u) << 16);
}

// ---------------------------------------------------------------------------
// Convert the 9 weight matrices to bf16, 128x128 row-major each, into ws.
// order: 0 Wp, 1 Wc, 2 W1a, 3 W1b, 4 W1c, 5 Wrel_ab, 6 Wroot_ab, 7 Wrel_ba, 8 Wroot_ba
// ---------------------------------------------------------------------------
__global__ __launch_bounds__(256) void prep_weights(
    const float* __restrict__ Wp, const float* __restrict__ Wc,
    const float* __restrict__ W1,
    const float* __restrict__ Wrel_ab, const float* __restrict__ Wroot_ab,
    const float* __restrict__ Wrel_ba, const float* __restrict__ Wroot_ba,
    u16* __restrict__ out)
{
  int tid = blockIdx.x * 256 + threadIdx.x;       // 9*16384 total
  int m = tid >> 14;
  int idx = tid & 16383;
  int r = idx >> 7;
  int c = idx & 127;
  float val;
  switch (m) {
    case 0: val = Wp[r * 128 + c]; break;
    case 1: val = Wc[r * 128 + c]; break;
    case 2: val = W1[r * 384 + c]; break;
    case 3: val = W1[r * 384 + 128 + c]; break;
    case 4: val = W1[r * 384 + 256 + c]; break;
    case 5: val = Wrel_ab[r * 128 + c]; break;
    case 6: val = Wroot_ab[r * 128 + c]; break;
    case 7: val = Wrel_ba[r * 128 + c]; break;
    default: val = Wroot_ba[r * 128 + c]; break;
  }
  out[tid] = f2bf(val);
}

// ---------------------------------------------------------------------------
// C[M,128] = act( A[M,128] @ W^T + bias1 + bias2 (+ addend) )
// W is 128x128 bf16 row-major (so B[k][n] = W[n][k]).
// One wave computes 16 rows x 128 cols with 32 MFMAs (16x16x32 bf16).
// ---------------------------------------------------------------------------
__global__ __launch_bounds__(256) void gemm128(
    const void* __restrict__ Ap, int a_bf16,
    const u16* __restrict__ Wb,
    const float* __restrict__ bias1,
    const float* __restrict__ bias2,
    const float* __restrict__ addend,
    void* __restrict__ outp, int out_bf16,
    int M, int act)
{
  int wave = blockIdx.x * 4 + (threadIdx.x >> 6);
  int row0 = wave * 16;
  if (row0 >= M) return;
  int lane = threadIdx.x & 63;
  int col = lane & 15;
  int quad = lane >> 4;

  // A fragments: lane holds A[row0+col][ks*32 + quad*8 + j]
  bf16x8 af[4];
  if (a_bf16) {
    const u16* A = (const u16*)Ap + (size_t)(row0 + col) * 128;
#pragma unroll
    for (int ks = 0; ks < 4; ks++)
      af[ks] = *(const bf16x8*)(A + ks * 32 + quad * 8);
  } else {
    const float* A = (const float*)Ap + (size_t)(row0 + col) * 128;
#pragma unroll
    for (int ks = 0; ks < 4; ks++) {
      const float* p = A + ks * 32 + quad * 8;
      f32x4 x0 = *(const f32x4*)p;
      f32x4 x1 = *(const f32x4*)(p + 4);
#pragma unroll
      for (int j = 0; j < 4; j++) {
        af[ks][j]     = (short)f2bf(x0[j]);
        af[ks][j + 4] = (short)f2bf(x1[j]);
      }
    }
  }

  f32x4 zero = {0.f, 0.f, 0.f, 0.f};
  f32x4 acc[8];
#pragma unroll
  for (int nt = 0; nt < 8; nt++) acc[nt] = zero;

#pragma unroll
  for (int ks = 0; ks < 4; ks++) {
    const u16* wp = Wb + col * 128 + ks * 32 + quad * 8;
#pragma unroll
    for (int nt = 0; nt < 8; nt++) {
      bf16x8 bf = *(const bf16x8*)(wp + nt * 16 * 128);
      acc[nt] = __builtin_amdgcn_mfma_f32_16x16x32_bf16(af[ks], bf, acc[nt], 0, 0, 0);
    }
  }

  // epilogue: C/D layout col=lane&15, row=quad*4+r
#pragma unroll
  for (int nt = 0; nt < 8; nt++) {
    int c = nt * 16 + col;
    float b = 0.f;
    if (bias1) b += bias1[c];
    if (bias2) b += bias2[c];
#pragma unroll
    for (int r = 0; r < 4; r++) {
      size_t row = row0 + quad * 4 + r;
      float val = acc[nt][r] + b;
      if (addend) val += addend[row * 128 + c];
      if (act == 1) val = val > 0.f ? val : 0.01f * val;
      if (out_bf16) ((u16*)outp)[row * 128 + c] = f2bf(val);
      else          ((float*)outp)[row * 128 + c] = val;
    }
  }
}

// ---------------------------------------------------------------------------
// Fused per-edge kernel. Wave handles 16 edges:
//   d = |x_s[src] - x_d[dst]|  (bf16 A-frag)
//   t = d @ W1c^T              (MFMA)
//   q = t + u[src] + v[dst] + b1 ; h = relu(q) ; w = sigmoid(h . W2 + b2)
//   msg[dst] += x_s[src] * w   (atomic fp32)
// ---------------------------------------------------------------------------
__global__ __launch_bounds__(256) void edge_fused(
    const float* __restrict__ xs,
    const float* __restrict__ xd,
    const int* __restrict__ ei,       // [2, E]
    const u16* __restrict__ W1c,
    const u16* __restrict__ u,        // N x 128 bf16
    const u16* __restrict__ v,        // N x 128 bf16
    const float* __restrict__ b1,
    const float* __restrict__ W2,
    const float* __restrict__ b2p,
    float* __restrict__ msg,          // N x 128 fp32, pre-zeroed
    int E)
{
  int wave = blockIdx.x * 4 + (threadIdx.x >> 6);
  int e0 = wave * 16;
  if (e0 >= E) return;
  int lane = threadIdx.x & 63;
  int col = lane & 15;
  int quad = lane >> 4;

  int em = e0 + col;
  if (em >= E) em = E - 1;
  int sidx = ei[em];
  int didx = ei[E + em];

  // A-fragments: |par - cld| in bf16
  bf16x8 af[4];
#pragma unroll
  for (int ks = 0; ks < 4; ks++) {
    const float* ps = xs + (size_t)sidx * 128 + ks * 32 + quad * 8;
    const float* pd = xd + (size_t)didx * 128 + ks * 32 + quad * 8;
    f32x4 s0 = *(const f32x4*)ps, s1 = *(const f32x4*)(ps + 4);
    f32x4 d0 = *(const f32x4*)pd, d1 = *(const f32x4*)(pd + 4);
#pragma unroll
    for (int j = 0; j < 4; j++) {
      af[ks][j]     = (short)f2bf(__builtin_fabsf(s0[j] - d0[j]));
      af[ks][j + 4] = (short)f2bf(__builtin_fabsf(s1[j] - d1[j]));
    }
  }

  f32x4 zero = {0.f, 0.f, 0.f, 0.f};
  f32x4 acc[8];
#pragma unroll
  for (int nt = 0; nt < 8; nt++) acc[nt] = zero;
#pragma unroll
  for (int ks = 0; ks < 4; ks++) {
    const u16* wp = W1c + col * 128 + ks * 32 + quad * 8;
#pragma unroll
    for (int nt = 0; nt < 8; nt++) {
      bf16x8 bf = *(const bf16x8*)(wp + nt * 2048);
      acc[nt] = __builtin_amdgcn_mfma_f32_16x16x32_bf16(af[ks], bf, acc[nt], 0, 0, 0);
    }
  }

  // C-row edge indices: row m = quad*4 + r  ->  edge e0 + m
  int esrc[4], edst[4];
  bool ev[4];
#pragma unroll
  for (int r = 0; r < 4; r++) {
    int e = e0 + quad * 4 + r;
    ev[r] = e < E;
    int ec = ev[r] ? e : E - 1;
    esrc[r] = ei[ec];
    edst[r] = ei[E + ec];
  }

  float sp[4] = {0.f, 0.f, 0.f, 0.f};
#pragma unroll
  for (int nt = 0; nt < 8; nt++) {
    int c = nt * 16 + col;
    float b1c = b1[c];
    float w2c = W2[c];
#pragma unroll
    for (int r = 0; r < 4; r++) {
      float q = acc[nt][r] + b1c + bf2f(u[(size_t)esrc[r] * 128 + c])
                                 + bf2f(v[(size_t)edst[r] * 128 + c]);
      float h = q > 0.f ? q : 0.f;
      sp[r] += h * w2c;
    }
  }
  // reduce across the 16 cols (lanes within the quad: xor of low 4 bits)
#pragma unroll
  for (int off = 1; off < 16; off <<= 1) {
#pragma unroll
    for (int r = 0; r < 4; r++) sp[r] += __shfl_xor(sp[r], off, 64);
  }

  float b2 = b2p[0];
#pragma unroll
  for (int r = 0; r < 4; r++) {
    if (!ev[r]) continue;
    float w = 1.f / (1.f + __expf(-(sp[r] + b2)));
    const float* pr = xs + (size_t)esrc[r] * 128;
    float* mr = msg + (size_t)edst[r] * 128;
#pragma unroll
    for (int nt = 0; nt < 8; nt++) {
      int c = nt * 16 + col;
      unsafeAtomicAdd(&mr[c], pr[c] * w);
    }
  }
}

// ---------------------------------------------------------------------------
extern "C" void kernel_launch(void* const* d_in, const int* in_sizes, int n_in,
                              void* d_out, int out_size, void* d_ws, size_t ws_size,
                              hipStream_t stream) {
  const float* x_a      = (const float*)d_in[0];
  const float* x_b      = (const float*)d_in[1];
  const float* Wp       = (const float*)d_in[2];
  const float* bp       = (const float*)d_in[3];
  const float* Wc       = (const float*)d_in[4];
  const float* bc       = (const float*)d_in[5];
  const float* W1       = (const float*)d_in[6];
  const float* b1       = (const float*)d_in[7];
  const float* W2       = (const float*)d_in[8];
  const float* b2       = (const float*)d_in[9];
  const float* Wrel_ab  = (const float*)d_in[10];
  const float* brel_ab  = (const float*)d_in[11];
  const float* Wroot_ab = (const float*)d_in[12];
  const float* broot_ab = (const float*)d_in[13];
  const float* Wrel_ba  = (const float*)d_in[14];
  const float* brel_ba  = (const float*)d_in[15];
  const float* Wroot_ba = (const float*)d_in[16];
  const float* broot_ba = (const float*)d_in[17];
  const int*   ei_ab    = (const int*)d_in[18];
  const int*   ei_ba    = (const int*)d_in[19];

  char* ws = (char*)d_ws;
  u16* Wb        = (u16*)ws;              // 9 * 16384 bf16 = 288 KB
  u16* Wp_b      = Wb + 0 * 16384;
  u16* Wc_b      = Wb + 1 * 16384;
  u16* W1a_b     = Wb + 2 * 16384;
  u16* W1b_b     = Wb + 3 * 16384;
  u16* W1c_b     = Wb + 4 * 16384;
  u16* Wrelab_b  = Wb + 5 * 16384;
  u16* Wrootab_b = Wb + 6 * 16384;
  u16* Wrelba_b  = Wb + 7 * 16384;
  u16* Wrootba_b = Wb + 8 * 16384;

  u16* ep    = (u16*)(ws + 1048576);      // 12.8 MB scratch (bf16 50000x128)
  u16* u_a   = (u16*)(ws + 13848576);
  u16* v_a   = (u16*)(ws + 26648576);
  u16* u_b   = (u16*)(ws + 39448576);
  u16* v_b   = (u16*)(ws + 52248576);
  float* msg_a = (float*)(ws + 65048576); // fp32 25.6 MB
  float* msg_b = (float*)(ws + 90648576);

  float* out_a = (float*)d_out;
  float* out_b = out_a + (size_t)N_NODES * 128;

  // zero both msg accumulators (contiguous)
  hipMemsetAsync(msg_a, 0, (size_t)2 * N_NODES * 128 * sizeof(float), stream);

  prep_weights<<<576, 256, 0, stream>>>(Wp, Wc, W1, Wrel_ab, Wroot_ab,
                                        Wrel_ba, Wroot_ba, Wb);

  const int GB = 782;   // ceil((50000/16)/4) waves->blocks

  // encoder pipelines: u = lrelu(x@Wp^T+bp) @ W1a^T ; v = lrelu(x@Wc^T+bc) @ W1b^T
  gemm128<<<GB, 256, 0, stream>>>(x_a, 0, Wp_b, bp, nullptr, nullptr, ep, 1, N_NODES, 1);
  gemm128<<<GB, 256, 0, stream>>>(ep, 1, W1a_b, nullptr, nullptr, nullptr, u_a, 1, N_NODES, 0);
  gemm128<<<GB, 256, 0, stream>>>(x_a, 0, Wc_b, bc, nullptr, nullptr, ep, 1, N_NODES, 1);
  gemm128<<<GB, 256, 0, stream>>>(ep, 1, W1b_b, nullptr, nullptr, nullptr, v_a, 1, N_NODES, 0);
  gemm128<<<GB, 256, 0, stream>>>(x_b, 0, Wp_b, bp, nullptr, nullptr, ep, 1, N_NODES, 1);
  gemm128<<<GB, 256, 0, stream>>>(ep, 1, W1a_b, nullptr, nullptr, nullptr, u_b, 1, N_NODES, 0);
  gemm128<<<GB, 256, 0, stream>>>(x_b, 0, Wc_b, bc, nullptr, nullptr, ep, 1, N_NODES, 1);
  gemm128<<<GB, 256, 0, stream>>>(ep, 1, W1b_b, nullptr, nullptr, nullptr, v_b, 1, N_NODES, 0);

  const int EB = 7813;  // ceil((500000/16)/4)
  // A->B: src=A (parent enc), dst=B (child enc), accumulate msg_b
  edge_fused<<<EB, 256, 0, stream>>>(x_a, x_b, ei_ab, W1c_b, u_a, v_b, b1, W2, b2, msg_b, EDGES);
  // B->A
  edge_fused<<<EB, 256, 0, stream>>>(x_b, x_a, ei_ba, W1c_b, u_b, v_a, b1, W2, b2, msg_a, EDGES);

  // out_a = msg_a @ Wrel_ba^T + brel_ba + x_a @ Wroot_ba^T + broot_ba
  gemm128<<<GB, 256, 0, stream>>>(x_a, 0, Wrootba_b, brel_ba, broot_ba, nullptr, out_a, 0, N_NODES, 0);
  gemm128<<<GB, 256, 0, stream>>>(msg_a, 0, Wrelba_b, nullptr, nullptr, out_a, out_a, 0, N_NODES, 0);
  // out_b
  gemm128<<<GB, 256, 0, stream>>>(x_b, 0, Wrootab_b, brel_ab, broot_ab, nullptr, out_b, 0, N_NODES, 0);
  gemm128<<<GB, 256, 0, stream>>>(msg_b, 0, Wrelab_b, nullptr, nullptr, out_b, out_b, 0, N_NODES, 0);
}